// Round 6
// baseline (3143.230 us; speedup 1.0000x reference)
//
#include <hip/hip_runtime.h>
#include <hip/hip_bf16.h>
#include <cstdint>

#define B_   128
#define T_   80
#define E_   100
#define U_   2048
#define G4_  8192

// fragment counts (32-wide K frags)
#define KB_L0  72    // 8 x-frags (E pad 256) + 64 h-frags
#define KB_L1  128   // 64 h0-frags + 64 h1-frags
#define STR0   (8 * KB_L0 * 512)   // ushorts per L0in time-slot

typedef __attribute__((ext_vector_type(8))) short bf16x8;
typedef __attribute__((ext_vector_type(4))) float f32x4;

__device__ __forceinline__ ushort f2bf(float x) {
    __hip_bfloat16 h = __float2bfloat16(x);
    return *reinterpret_cast<ushort*>(&h);
}

// ---------------- embedding -> x frags [0..8) of L0in[t], packed ------------
__global__ __launch_bounds__(256)
void embed_pack(const int* __restrict__ tokens, const float* __restrict__ emb,
                ushort* __restrict__ L0in) {
    int gtid = blockIdx.x * 256 + threadIdx.x;   // one 8-ushort chunk each
    if (gtid >= T_ * 8 * 8 * 64) return;
    int lane = gtid & 63;
    int rest = gtid >> 6;
    int i    = rest & 7;  rest >>= 3;
    int mtg  = rest & 7;
    int t    = rest >> 3;
    int row  = (mtg >> 2) * 64 + (mtg & 3) * 16 + (lane & 15);
    int k0   = i * 32 + (lane >> 4) * 8;
    const float* erow = emb + (size_t)tokens[row * T_ + t] * E_;
    ushort v[8];
#pragma unroll
    for (int j = 0; j < 8; ++j) {
        int e = k0 + j;
        v[j] = f2bf(e < E_ ? erow[e] : 0.f);
    }
    ushort* dst = L0in + (size_t)t * STR0 + ((size_t)(mtg * KB_L0 + i)) * 512 + lane * 8;
    *reinterpret_cast<uint4*>(dst) = *reinterpret_cast<const uint4*>(v);
}

// ---------------- weight pack into concatenated B-frag layout ---------------
// out[((ut*KBtot + koff + i)*NG + g)*512 + lane*8 + j] = W[k][g*U_ + ut*16 + (lane&15)]
//   k = i*32 + (lane>>4)*8 + j, zero-padded for k >= K
__global__ __launch_bounds__(256)
void pack_w(const float* __restrict__ W, int K, int Ncols, int NG,
            int KBtot, int koff, int KBthis, ushort* __restrict__ out) {
    int gtid = blockIdx.x * 256 + threadIdx.x;
    int lane = gtid & 63;
    int rest = gtid >> 6;
    int g = rest % NG; rest /= NG;
    int i = rest % KBthis;
    int ut = rest / KBthis;
    if (ut >= U_ / 16) return;
    int col = g * U_ + ut * 16 + (lane & 15);
    int k0 = i * 32 + (lane >> 4) * 8;
    ushort v[8];
#pragma unroll
    for (int j = 0; j < 8; ++j) {
        int k = k0 + j;
        v[j] = f2bf(k < K ? W[(size_t)k * Ncols + col] : 0.f);
    }
    ushort* dst = out + ((size_t)(ut * KBtot + koff + i) * NG + g) * 512 + lane * 8;
    *reinterpret_cast<uint4*>(dst) = *reinterpret_cast<const uint4*>(v);
}

// ---------------- fused LSTM step: single concatenated stream ---------------
// grid 256 = mh(2) x ut(128); block 512 = 8 waves (kq). Wave kq: 16 MFMA/iter
// over its K-eighth, depth-3 register pipeline, branch-free addressing.
// Epilogue writes h into up to two packed destinations (next consumers).
template<int KBT>
__global__ __launch_bounds__(512)
void lstm_fused(const ushort* __restrict__ Ain,   // [8 mtg][KBT][512]
                const ushort* __restrict__ Wcat,  // [128 ut][KBT][4][512]
                const float* __restrict__ bias,
                float* __restrict__ c,
                ushort* __restrict__ d1, int kbt1, int off1,
                ushort* __restrict__ d2, int kbt2, int off2) {
    constexpr int NIT = KBT / 8;
    const int tid  = threadIdx.x;
    const int lane = tid & 63;
    const int kq   = tid >> 6;     // 0..7
    const int ut   = blockIdx.x & 127;
    const int mh   = blockIdx.x >> 7;
    const int beg  = kq * NIT;

    const ushort* a = Ain  + ((size_t)(mh * 4) * KBT + beg) * 512 + lane * 8;
    const ushort* w = Wcat + ((size_t)(ut * KBT + beg) * 4) * 512 + lane * 8;

    f32x4 acc[4][4];   // [gate][mt]
#pragma unroll
    for (int g = 0; g < 4; ++g)
#pragma unroll
        for (int mt = 0; mt < 4; ++mt) acc[g][mt] = f32x4{0.f, 0.f, 0.f, 0.f};

    bf16x8 Ab[3][4], Bb[3][4];
#define LOADI(ii, AD, BD)                                                        \
    {                                                                            \
        _Pragma("unroll")                                                        \
        for (int mt = 0; mt < 4; ++mt)                                           \
            AD[mt] = *reinterpret_cast<const bf16x8*>(a + ((size_t)mt * KBT + (ii)) * 512); \
        _Pragma("unroll")                                                        \
        for (int g = 0; g < 4; ++g)                                              \
            BD[g] = *reinterpret_cast<const bf16x8*>(w + (size_t)((ii) * 4 + g) * 512);     \
    }

    LOADI(0, Ab[0], Bb[0]);
    LOADI(1, Ab[1], Bb[1]);
#pragma unroll
    for (int ii = 0; ii < NIT; ++ii) {
        if (ii + 2 < NIT) {
            const int s = (ii + 2) % 3;
            LOADI(ii + 2, Ab[s], Bb[s]);
        }
        const int p = ii % 3;
#pragma unroll
        for (int g = 0; g < 4; ++g)
#pragma unroll
            for (int mt = 0; mt < 4; ++mt)
                acc[g][mt] = __builtin_amdgcn_mfma_f32_16x16x32_bf16(
                    Ab[p][mt], Bb[p][g], acc[g][mt], 0, 0, 0);
    }
#undef LOADI

    // kq-partial reduction: 2 gates per round through 64KB LDS
    __shared__ float zs[8][64][32];
    const int lr = tid >> 3;          // 0..63
    const int u0 = (tid & 7) * 2;     // 0,2,..,14
    float zred[4][2];
#pragma unroll
    for (int rnd = 0; rnd < 2; ++rnd) {
        if (rnd) __syncthreads();
#pragma unroll
        for (int gg = 0; gg < 2; ++gg) {
            const int g = rnd * 2 + gg;
#pragma unroll
            for (int mt = 0; mt < 4; ++mt)
#pragma unroll
                for (int r = 0; r < 4; ++r)
                    zs[kq][mt * 16 + (lane >> 4) * 4 + r][gg * 16 + (lane & 15)] = acc[g][mt][r];
        }
        __syncthreads();
#pragma unroll
        for (int gg = 0; gg < 2; ++gg) {
            float s0 = 0.f, s1 = 0.f;
#pragma unroll
            for (int w8 = 0; w8 < 8; ++w8) {
                s0 += zs[w8][lr][gg * 16 + u0];
                s1 += zs[w8][lr][gg * 16 + u0 + 1];
            }
            zred[rnd * 2 + gg][0] = s0;
            zred[rnd * 2 + gg][1] = s1;
        }
    }

    // fused cell update for 2 units
    const int grow = mh * 64 + lr;
    const int unit = ut * 16 + u0;
    const float2 bi  = *reinterpret_cast<const float2*>(&bias[unit]);
    const float2 bfv = *reinterpret_cast<const float2*>(&bias[U_ + unit]);
    const float2 bgv = *reinterpret_cast<const float2*>(&bias[2 * U_ + unit]);
    const float2 bov = *reinterpret_cast<const float2*>(&bias[3 * U_ + unit]);
    float2 cv = *reinterpret_cast<float2*>(&c[(size_t)grow * U_ + unit]);

    float cn[2];
    ushort hv[2];
#pragma unroll
    for (int e = 0; e < 2; ++e) {
        float zi = zred[0][e] + (e ? bi.y : bi.x);
        float zf = zred[1][e] + (e ? bfv.y : bfv.x);
        float zg = zred[2][e] + (e ? bgv.y : bgv.x);
        float zo = zred[3][e] + (e ? bov.y : bov.x);
        float si = 1.f / (1.f + __expf(-zi));
        float sf = 1.f / (1.f + __expf(-zf));
        float so = 1.f / (1.f + __expf(-zo));
        float tg = tanhf(zg);
        float cc = sf * (e ? cv.y : cv.x) + si * tg;
        cn[e] = cc;
        hv[e] = f2bf(so * tanhf(cc));
    }
    *reinterpret_cast<float2*>(&c[(size_t)grow * U_ + unit]) = make_float2(cn[0], cn[1]);

    // packed h writes into consumer input slots
    const int mt = lr >> 4;
    const int cl = lr & 15;
    const int fr = unit >> 5;                    // 0..63
    const int lp = ((unit >> 3) & 3) * 16 + cl;
    const int jj = unit & 7;                     // even
    const ushort2 hv2 = make_ushort2(hv[0], hv[1]);
    {
        size_t fi = (size_t)(mh * 4 + mt) * kbt1 + off1 + fr;
        *reinterpret_cast<ushort2*>(&d1[fi * 512 + lp * 8 + jj]) = hv2;
    }
    if (d2) {
        size_t fi = (size_t)(mh * 4 + mt) * kbt2 + off2 + fr;
        *reinterpret_cast<ushort2*>(&d2[fi * 512 + lp * 8 + jj]) = hv2;
    }
}

// ---------------- head: y = relu(h1 @ Wd + bd); h1 = L1in[0] frags [64..128) -
__global__ __launch_bounds__(256)
void head_mfma(const ushort* __restrict__ h1p, const ushort* __restrict__ Wdp,
               const float* __restrict__ bd, float* __restrict__ y) {
    const int lane = threadIdx.x & 63;
    const int w    = threadIdx.x >> 6;  // k-split wave
    const int ut   = blockIdx.x & 127;
    const int mh   = blockIdx.x >> 7;

    const ushort* ap = h1p + ((size_t)(mh * 4) * KB_L1 + 64) * 512 + lane * 8;
    const ushort* wp = Wdp + (size_t)(ut * 64 + w * 16) * 512 + lane * 8;

    f32x4 acc[4];
#pragma unroll
    for (int mt = 0; mt < 4; ++mt) acc[mt] = f32x4{0.f, 0.f, 0.f, 0.f};

    auto LOADH = [&](int i, bf16x8* a, bf16x8& b) {
        b = *reinterpret_cast<const bf16x8*>(wp + (size_t)i * 512);
        int kb = w * 16 + i;
#pragma unroll
        for (int mt = 0; mt < 4; ++mt)
            a[mt] = *reinterpret_cast<const bf16x8*>(ap + (size_t)(mt * KB_L1 + kb) * 512);
    };

    bf16x8 aA[4], bA, aB[4], bB;
    LOADH(0, aA, bA);
    for (int i = 0; i < 16; i += 2) {
        LOADH(i + 1, aB, bB);
#pragma unroll
        for (int mt = 0; mt < 4; ++mt)
            acc[mt] = __builtin_amdgcn_mfma_f32_16x16x32_bf16(aA[mt], bA, acc[mt], 0, 0, 0);
        if (i + 2 < 16) LOADH(i + 2, aA, bA);
#pragma unroll
        for (int mt = 0; mt < 4; ++mt)
            acc[mt] = __builtin_amdgcn_mfma_f32_16x16x32_bf16(aB[mt], bB, acc[mt], 0, 0, 0);
    }

    __shared__ float zs[4][64][16];
#pragma unroll
    for (int mt = 0; mt < 4; ++mt)
#pragma unroll
        for (int r = 0; r < 4; ++r)
            zs[w][mt * 16 + (lane >> 4) * 4 + r][lane & 15] = acc[mt][r];
    __syncthreads();

    const int tid = threadIdx.x;
    const int lr  = tid >> 2;
    const int u4  = (tid & 3) * 4;
    const int grow = mh * 64 + lr;
    const int gu   = ut * 16 + u4;

    float4 s0 = *reinterpret_cast<float4*>(&zs[0][lr][u4]);
    float4 s1 = *reinterpret_cast<float4*>(&zs[1][lr][u4]);
    float4 s2 = *reinterpret_cast<float4*>(&zs[2][lr][u4]);
    float4 s3 = *reinterpret_cast<float4*>(&zs[3][lr][u4]);
    const float4 bb = *reinterpret_cast<const float4*>(&bd[gu]);
    float4 r;
    r.x = s0.x + s1.x + s2.x + s3.x + bb.x;
    r.y = s0.y + s1.y + s2.y + s3.y + bb.y;
    r.z = s0.z + s1.z + s2.z + s3.z + bb.z;
    r.w = s0.w + s1.w + s2.w + s3.w + bb.w;
    r.x = r.x > 0.f ? r.x : 0.f;
    r.y = r.y > 0.f ? r.y : 0.f;
    r.z = r.z > 0.f ? r.z : 0.f;
    r.w = r.w > 0.f ? r.w : 0.f;
    *reinterpret_cast<float4*>(&y[(size_t)grow * U_ + gu]) = r;
}

// ---------------- out[b] = sigmoid(y[b,:] @ Wo + bo) ----------------
__global__ __launch_bounds__(256)
void head2(const float* __restrict__ y, const float* __restrict__ Wo,
           const float* __restrict__ bo, float* __restrict__ out) {
    __shared__ float red[256];
    const int b = blockIdx.x;
    const int tid = threadIdx.x;
    float s = 0.f;
    for (int u = tid; u < U_; u += 256) s += y[(size_t)b * U_ + u] * Wo[u];
    red[tid] = s;
    __syncthreads();
    for (int off = 128; off > 0; off >>= 1) {
        if (tid < off) red[tid] += red[tid + off];
        __syncthreads();
    }
    if (tid == 0) out[b] = 1.f / (1.f + __expf(-(red[0] + bo[0])));
}

extern "C" void kernel_launch(void* const* d_in, const int* in_sizes, int n_in,
                              void* d_out, int out_size, void* d_ws, size_t ws_size,
                              hipStream_t stream) {
    const int*   tokens = (const int*)  d_in[0];
    const float* emb    = (const float*)d_in[1];
    const float* W0     = (const float*)d_in[2];
    const float* U0     = (const float*)d_in[3];
    const float* b0     = (const float*)d_in[4];
    const float* W1     = (const float*)d_in[5];
    const float* U1     = (const float*)d_in[6];
    const float* b1     = (const float*)d_in[7];
    const float* Wd     = (const float*)d_in[8];
    const float* bd     = (const float*)d_in[9];
    const float* Wo     = (const float*)d_in[10];
    const float* bo     = (const float*)d_in[11];

    // ws layout (bytes); total ~159 MB
    char* base = (char*)d_ws;
    float*  c0    = (float*) (base + 0);           // 1 MB
    float*  c1    = (float*) (base + 1048576);     // 1 MB
    ushort* L1in0 = (ushort*)(base + 2097152);     // 1 MB
    ushort* L1in1 = (ushort*)(base + 3145728);     // 1 MB
    ushort* L0in  = (ushort*)(base + 4194304);     // 81 x 589,824 B = 47,775,744
    ushort* Wcat0 = (ushort*)(base + 51970048);    // 36 MB
    ushort* Wcat1 = (ushort*)(base + 89718784);    // 64 MB
    ushort* Wdp   = (ushort*)(base + 156827648);   //  8 MB
    float*  yb    = (float*) (base + 165216256);   //  1 MB

    ushort* L1in[2] = {L1in0, L1in1};

    // zero c0, c1, L1in0, L1in1, L0in[0]  (one contiguous 4,784,128-byte memset)
    hipMemsetAsync(d_ws, 0, 4784128, stream);

    embed_pack<<<(T_ * 8 * 8 * 64 + 255) / 256, 256, 0, stream>>>(tokens, emb, L0in);
    // Wcat0 = [W0 (8 frags) | U0 (64 frags)] per ut, 4 gates
    pack_w<<<1024, 256, 0, stream>>>(W0, E_, G4_, 4, KB_L0, 0, 8,  Wcat0);
    pack_w<<<8192, 256, 0, stream>>>(U0, U_, G4_, 4, KB_L0, 8, 64, Wcat0);
    // Wcat1 = [W1 (64) | U1 (64)]
    pack_w<<<8192, 256, 0, stream>>>(W1, U_, G4_, 4, KB_L1, 0,  64, Wcat1);
    pack_w<<<8192, 256, 0, stream>>>(U1, U_, G4_, 4, KB_L1, 64, 64, Wcat1);
    // Wd: single "gate", 64 frags
    pack_w<<<2048, 256, 0, stream>>>(Wd, U_, U_, 1, 64, 0, 64, Wdp);

    for (int t = 0; t < T_; ++t) {
        // layer 0: reads L0in[t]; h0 -> L0in[t+1] frags[8..72) and L1in[t&1] frags[0..64)
        lstm_fused<KB_L0><<<256, 512, 0, stream>>>(
            L0in + (size_t)t * STR0, Wcat0, b0, c0,
            L0in + (size_t)(t + 1) * STR0, KB_L0, 8,
            L1in[t & 1], KB_L1, 0);
        // layer 1: reads L1in[t&1]; h1 -> L1in[(t+1)&1] frags[64..128)
        lstm_fused<KB_L1><<<256, 512, 0, stream>>>(
            L1in[t & 1], Wcat1, b1, c1,
            L1in[(t + 1) & 1], KB_L1, 64,
            nullptr, 0, 0);
    }
    // final h1 lives in L1in[0] frags [64..128)
    head_mfma<<<256, 256, 0, stream>>>(L1in[0], Wdp, bd, yb);
    head2<<<B_, 256, 0, stream>>>(yb, Wo, bo, (float*)d_out);
}

// Round 7
// 2284.665 us; speedup vs baseline: 1.3758x; 1.3758x over previous
//
#include <hip/hip_runtime.h>
#include <hip/hip_bf16.h>
#include <cstdint>

#define B_   128
#define T_   80
#define E_   100
#define U_   2048
#define G4_  8192

typedef __attribute__((ext_vector_type(8))) short bf16x8;
typedef __attribute__((ext_vector_type(4))) float f32x4;

__device__ __forceinline__ ushort f2bf(float x) {
    __hip_bfloat16 h = __float2bfloat16(x);
    return *reinterpret_cast<ushort*>(&h);
}

// ---------------- embedding -> A-fragment-packed bf16 X (kb0 = 8 frags) -----
__global__ __launch_bounds__(256)
void embed_pack(const int* __restrict__ tokens, const float* __restrict__ emb,
                ushort* __restrict__ Xp) {
    int gtid = blockIdx.x * 256 + threadIdx.x;   // one 8-ushort chunk each
    if (gtid >= T_ * 8 * 8 * 64) return;
    int lane = gtid & 63;
    int rest = gtid >> 6;
    int i    = rest & 7;  rest >>= 3;
    int mtg  = rest & 7;
    int t    = rest >> 3;
    int row  = (mtg >> 2) * 64 + (mtg & 3) * 16 + (lane & 15);
    int k0   = i * 32 + (lane >> 4) * 8;
    const float* erow = emb + (size_t)tokens[row * T_ + t] * E_;
    ushort v[8];
#pragma unroll
    for (int j = 0; j < 8; ++j) {
        int e = k0 + j;
        v[j] = f2bf(e < E_ ? erow[e] : 0.f);
    }
    *reinterpret_cast<uint4*>(Xp + (size_t)gtid * 8) = *reinterpret_cast<const uint4*>(v);
}

// ---------------- weight pack: fp32 [K][Ncols] -> bf16 MFMA B-frag layout ----
__global__ __launch_bounds__(256)
void pack_w(const float* __restrict__ W, int K, int Ncols, int NG, int KB,
            ushort* __restrict__ out) {
    int gtid = blockIdx.x * 256 + threadIdx.x;
    int lane = gtid & 63;
    int rest = gtid >> 6;
    int g = rest % NG; rest /= NG;
    int i = rest % KB;
    int ut = rest / KB;
    if (ut >= U_ / 16) return;
    int col = g * U_ + ut * 16 + (lane & 15);
    int k0 = i * 32 + (lane >> 4) * 8;
    ushort v[8];
#pragma unroll
    for (int j = 0; j < 8; ++j) {
        int k = k0 + j;
        v[j] = f2bf(k < K ? W[(size_t)k * Ncols + col] : 0.f);
    }
    *reinterpret_cast<uint4*>(out + (size_t)gtid * 8) = *reinterpret_cast<const uint4*>(v);
}

// ---------------- fused LSTM step, wave = K-eighth, all 4 gates per wave -----
// grid 256; XCD-swizzled so the two mh-twins of each ut sit on the same XCD
// in adjacent slots (shared per-XCD L2 weight stream). 8 waves (kq 0..7),
// 16 MFMA/iter, depth-1 double-buffer; s_setprio(1) around MFMA clusters.
__global__ __launch_bounds__(512)
void lstm_step_mfma(const ushort* __restrict__ A0p, int kb0,
                    const ushort* __restrict__ Wp0,
                    const ushort* __restrict__ A1p, int kb1,
                    const ushort* __restrict__ Wp1,
                    const float* __restrict__ bias,
                    float* __restrict__ c,
                    ushort* __restrict__ h_out /* packed */) {
    const int tid  = threadIdx.x;
    const int lane = tid & 63;
    const int kq   = tid >> 6;     // 0..7
    // XCD-aware remap: xcd = b&7 owns ut in [xcd*16, xcd*16+16); twins adjacent
    const int b    = blockIdx.x;
    const int s    = b >> 3;
    const int ut   = (b & 7) * 16 + (s >> 1);
    const int mh   = s & 1;

    const ushort* a0 = A0p + ((size_t)(mh * 4) * kb0) * 512 + lane * 8;
    const ushort* a1 = A1p + ((size_t)(mh * 4) * kb1) * 512 + lane * 8;
    const ushort* w0 = Wp0 + ((size_t)(ut * kb0) * 4) * 512 + lane * 8;
    const ushort* w1 = Wp1 + ((size_t)(ut * kb1) * 4) * 512 + lane * 8;

    f32x4 acc[4][4];   // [gate][mt]
#pragma unroll
    for (int g = 0; g < 4; ++g)
#pragma unroll
        for (int mt = 0; mt < 4; ++mt) acc[g][mt] = f32x4{0.f, 0.f, 0.f, 0.f};

    auto LOAD = [&](int i, bf16x8* a, bf16x8* bfr) {
        if (i < kb0) {
#pragma unroll
            for (int mt = 0; mt < 4; ++mt)
                a[mt] = *reinterpret_cast<const bf16x8*>(a0 + (size_t)(mt * kb0 + i) * 512);
#pragma unroll
            for (int g = 0; g < 4; ++g)
                bfr[g] = *reinterpret_cast<const bf16x8*>(w0 + (size_t)(i * 4 + g) * 512);
        } else {
            int ii = i - kb0;
#pragma unroll
            for (int mt = 0; mt < 4; ++mt)
                a[mt] = *reinterpret_cast<const bf16x8*>(a1 + (size_t)(mt * kb1 + ii) * 512);
#pragma unroll
            for (int g = 0; g < 4; ++g)
                bfr[g] = *reinterpret_cast<const bf16x8*>(w1 + (size_t)(ii * 4 + g) * 512);
        }
    };
#define MFMA_ALL(aa, bb)                                                         \
    {                                                                            \
        __builtin_amdgcn_s_setprio(1);                                           \
        _Pragma("unroll")                                                        \
        for (int g = 0; g < 4; ++g)                                              \
            _Pragma("unroll")                                                    \
            for (int mt = 0; mt < 4; ++mt)                                       \
                acc[g][mt] = __builtin_amdgcn_mfma_f32_16x16x32_bf16(            \
                    aa[mt], bb[g], acc[g][mt], 0, 0, 0);                         \
        __builtin_amdgcn_s_setprio(0);                                           \
    }

    const int KBt = kb0 + kb1;        // 72 or 128 (divisible by 8)
    const int KBq = KBt >> 3;
    const int beg = kq * KBq;
    const int end = beg + KBq;

    bf16x8 aA[4], bA[4], aB[4], bB[4];
    int i = beg;
    LOAD(i, aA, bA);
    for (; i + 1 < end; i += 2) {
        LOAD(i + 1, aB, bB);
        MFMA_ALL(aA, bA);
        if (i + 2 < end) LOAD(i + 2, aA, bA);
        MFMA_ALL(aB, bB);
    }
    if (i < end) MFMA_ALL(aA, bA);
#undef MFMA_ALL

    // kq-partial reduction, one gate at a time through a 32KB LDS buffer
    __shared__ float zs[8][64][16];
    const int lr = tid >> 3;          // 0..63
    const int u0 = (tid & 7) * 2;     // 0,2,..,14
    float zg2[4][2];
#pragma unroll
    for (int g = 0; g < 4; ++g) {
        __syncthreads();
#pragma unroll
        for (int mt = 0; mt < 4; ++mt)
#pragma unroll
            for (int r = 0; r < 4; ++r)
                zs[kq][mt * 16 + (lane >> 4) * 4 + r][lane & 15] = acc[g][mt][r];
        __syncthreads();
        float s0 = 0.f, s1 = 0.f;
#pragma unroll
        for (int w8 = 0; w8 < 8; ++w8) {
            s0 += zs[w8][lr][u0];
            s1 += zs[w8][lr][u0 + 1];
        }
        zg2[g][0] = s0;
        zg2[g][1] = s1;
    }

    // fused cell update for 2 units
    const int grow = mh * 64 + lr;
    const int unit = ut * 16 + u0;
    const float2 bi  = *reinterpret_cast<const float2*>(&bias[unit]);
    const float2 bfv = *reinterpret_cast<const float2*>(&bias[U_ + unit]);
    const float2 bgv = *reinterpret_cast<const float2*>(&bias[2 * U_ + unit]);
    const float2 bov = *reinterpret_cast<const float2*>(&bias[3 * U_ + unit]);
    float2 cv = *reinterpret_cast<float2*>(&c[(size_t)grow * U_ + unit]);

    float cn[2];
    ushort hv[2];
#pragma unroll
    for (int e = 0; e < 2; ++e) {
        float zi = zg2[0][e] + (e ? bi.y : bi.x);
        float zf = zg2[1][e] + (e ? bfv.y : bfv.x);
        float zg = zg2[2][e] + (e ? bgv.y : bgv.x);
        float zo = zg2[3][e] + (e ? bov.y : bov.x);
        float si = 1.f / (1.f + __expf(-zi));
        float sf = 1.f / (1.f + __expf(-zf));
        float so = 1.f / (1.f + __expf(-zo));
        float tg = tanhf(zg);
        float cc = sf * (e ? cv.y : cv.x) + si * tg;
        cn[e] = cc;
        hv[e] = f2bf(so * tanhf(cc));
    }
    *reinterpret_cast<float2*>(&c[(size_t)grow * U_ + unit]) = make_float2(cn[0], cn[1]);

    // packed h write (same layout as A-frags with kb=64)
    const int mt = lr >> 4;
    const int cl = lr & 15;
    const int fi = (mh * 4 + mt) * 64 + (unit >> 5);
    const int lp = ((unit >> 3) & 3) * 16 + cl;
    *reinterpret_cast<ushort2*>(&h_out[(size_t)fi * 512 + lp * 8 + (unit & 7)]) =
        make_ushort2(hv[0], hv[1]);
}

// ---------------- head: y = relu(h1 @ Wd + bd); h1 is fragment-packed -------
__global__ __launch_bounds__(256)
void head_mfma(const ushort* __restrict__ h1p, const ushort* __restrict__ Wdp,
               const float* __restrict__ bd, float* __restrict__ y) {
    const int lane = threadIdx.x & 63;
    const int w    = threadIdx.x >> 6;  // k-split wave
    const int ut   = blockIdx.x & 127;
    const int mh   = blockIdx.x >> 7;

    const ushort* ap = h1p + ((size_t)(mh * 4) * 64) * 512 + lane * 8;
    const ushort* wp = Wdp + (size_t)(ut * 64 + w * 16) * 512 + lane * 8;

    f32x4 acc[4];
#pragma unroll
    for (int mt = 0; mt < 4; ++mt) acc[mt] = f32x4{0.f, 0.f, 0.f, 0.f};

    auto LOADH = [&](int i, bf16x8* a, bf16x8& b) {
        b = *reinterpret_cast<const bf16x8*>(wp + (size_t)i * 512);
        int kb = w * 16 + i;
#pragma unroll
        for (int mt = 0; mt < 4; ++mt)
            a[mt] = *reinterpret_cast<const bf16x8*>(ap + (size_t)(mt * 64 + kb) * 512);
    };

    bf16x8 aA[4], bA, aB[4], bB;
    LOADH(0, aA, bA);
    for (int i = 0; i < 16; i += 2) {
        LOADH(i + 1, aB, bB);
#pragma unroll
        for (int mt = 0; mt < 4; ++mt)
            acc[mt] = __builtin_amdgcn_mfma_f32_16x16x32_bf16(aA[mt], bA, acc[mt], 0, 0, 0);
        if (i + 2 < 16) LOADH(i + 2, aA, bA);
#pragma unroll
        for (int mt = 0; mt < 4; ++mt)
            acc[mt] = __builtin_amdgcn_mfma_f32_16x16x32_bf16(aB[mt], bB, acc[mt], 0, 0, 0);
    }

    __shared__ float zs[4][64][16];
#pragma unroll
    for (int mt = 0; mt < 4; ++mt)
#pragma unroll
        for (int r = 0; r < 4; ++r)
            zs[w][mt * 16 + (lane >> 4) * 4 + r][lane & 15] = acc[mt][r];
    __syncthreads();

    const int tid = threadIdx.x;
    const int lr  = tid >> 2;
    const int u4  = (tid & 3) * 4;
    const int grow = mh * 64 + lr;
    const int gu   = ut * 16 + u4;

    float4 s0 = *reinterpret_cast<float4*>(&zs[0][lr][u4]);
    float4 s1 = *reinterpret_cast<float4*>(&zs[1][lr][u4]);
    float4 s2 = *reinterpret_cast<float4*>(&zs[2][lr][u4]);
    float4 s3 = *reinterpret_cast<float4*>(&zs[3][lr][u4]);
    const float4 bb = *reinterpret_cast<const float4*>(&bd[gu]);
    float4 r;
    r.x = s0.x + s1.x + s2.x + s3.x + bb.x;
    r.y = s0.y + s1.y + s2.y + s3.y + bb.y;
    r.z = s0.z + s1.z + s2.z + s3.z + bb.z;
    r.w = s0.w + s1.w + s2.w + s3.w + bb.w;
    r.x = r.x > 0.f ? r.x : 0.f;
    r.y = r.y > 0.f ? r.y : 0.f;
    r.z = r.z > 0.f ? r.z : 0.f;
    r.w = r.w > 0.f ? r.w : 0.f;
    *reinterpret_cast<float4*>(&y[(size_t)grow * U_ + gu]) = r;
}

// ---------------- out[b] = sigmoid(y[b,:] @ Wo + bo) ----------------
__global__ __launch_bounds__(256)
void head2(const float* __restrict__ y, const float* __restrict__ Wo,
           const float* __restrict__ bo, float* __restrict__ out) {
    __shared__ float red[256];
    const int b = blockIdx.x;
    const int tid = threadIdx.x;
    float s = 0.f;
    for (int u = tid; u < U_; u += 256) s += y[(size_t)b * U_ + u] * Wo[u];
    red[tid] = s;
    __syncthreads();
    for (int off = 128; off > 0; off >>= 1) {
        if (tid < off) red[tid] += red[tid + off];
        __syncthreads();
    }
    if (tid == 0) out[b] = 1.f / (1.f + __expf(-(red[0] + bo[0])));
}

extern "C" void kernel_launch(void* const* d_in, const int* in_sizes, int n_in,
                              void* d_out, int out_size, void* d_ws, size_t ws_size,
                              hipStream_t stream) {
    const int*   tokens = (const int*)  d_in[0];
    const float* emb    = (const float*)d_in[1];
    const float* W0     = (const float*)d_in[2];
    const float* U0     = (const float*)d_in[3];
    const float* b0     = (const float*)d_in[4];
    const float* W1     = (const float*)d_in[5];
    const float* U1     = (const float*)d_in[6];
    const float* b1     = (const float*)d_in[7];
    const float* Wd     = (const float*)d_in[8];
    const float* bd     = (const float*)d_in[9];
    const float* Wo     = (const float*)d_in[10];
    const float* bo     = (const float*)d_in[11];

    // ws layout (bytes); total ~117 MB
    char* base = (char*)d_ws;
    ushort* h0a = (ushort*)(base + 0);          //  512 KB (packed)
    ushort* h1a = (ushort*)(base + 524288);     //  512 KB (packed)
    float*  c0  = (float*) (base + 1048576);    // 1 MB
    float*  c1  = (float*) (base + 2097152);    // 1 MB
    ushort* h0b = (ushort*)(base + 3145728);
    ushort* h1b = (ushort*)(base + 3670016);
    ushort* Xp  = (ushort*)(base + 4194304);    // 5 MB (packed, kb0=8)
    float*  yb  = (float*) (base + 4194304);    // overlays Xp (Xp dead by head)
    ushort* W0p = (ushort*)(base + 9437184);    // 4 MB
    ushort* U0p = (ushort*)(base + 13631488);   // 32 MB
    ushort* W1p = (ushort*)(base + 47185920);   // 32 MB
    ushort* U1p = (ushort*)(base + 80740352);   // 32 MB
    ushort* Wdp = (ushort*)(base + 114294784);  // 8 MB

    // zero h0a, h1a, c0, c1 (contiguous 3 MB)
    hipMemsetAsync(d_ws, 0, 3145728, stream);

    embed_pack<<<(T_ * 8 * 8 * 64 + 255) / 256, 256, 0, stream>>>(tokens, emb, Xp);
    pack_w<<<1024, 256, 0, stream>>>(W0, E_, G4_, 4, 8,  W0p);
    pack_w<<<8192, 256, 0, stream>>>(U0, U_, G4_, 4, 64, U0p);
    pack_w<<<8192, 256, 0, stream>>>(W1, U_, G4_, 4, 64, W1p);
    pack_w<<<8192, 256, 0, stream>>>(U1, U_, G4_, 4, 64, U1p);
    pack_w<<<2048, 256, 0, stream>>>(Wd, U_, U_,  1, 64, Wdp);

    for (int t = 0; t < T_; ++t) {
        const ushort* h0in  = (t & 1) ? h0b : h0a;
        ushort*       h0out = (t & 1) ? h0a : h0b;
        const ushort* h1in  = (t & 1) ? h1b : h1a;
        ushort*       h1out = (t & 1) ? h1a : h1b;
        lstm_step_mfma<<<256, 512, 0, stream>>>(Xp + (size_t)t * 8 * 8 * 512, 8, W0p,
                                                h0in, 64, U0p, b0, c0, h0out);
        lstm_step_mfma<<<256, 512, 0, stream>>>(h0out, 64, W1p,
                                                h1in, 64, U1p, b1, c1, h1out);
    }
    // t=79 (odd) wrote the 'a' buffers
    head_mfma<<<256, 256, 0, stream>>>(h1a, Wdp, bd, yb);
    head2<<<B_, 256, 0, stream>>>(yb, Wo, bo, (float*)d_out);
}

// Round 8
// 1938.944 us; speedup vs baseline: 1.6211x; 1.1783x over previous
//
#include <hip/hip_runtime.h>
#include <hip/hip_bf16.h>
#include <hip/hip_fp8.h>
#include <cstdint>

#define B_   128
#define T_   80
#define E_   100
#define U_   2048
#define G4_  8192

// scales: A-side (x,h) x16, B-side (weights) x32; acc * 1/512 restores z
#define SA_   16.0f
#define SB_   32.0f
#define INV_SASB_ (1.0f / 512.0f)

typedef __attribute__((ext_vector_type(4))) float f32x4;

__device__ __forceinline__ unsigned char f2fp8(float x) {
    __hip_fp8_e4m3 q(x);
    return q.__x;
}

// ---------------- embedding -> A-fragment-packed fp8 X (kb0 = 8 frags) -----
// Xp[((t*8 + mtg)*8 + i)*512 + lane*8 + j] = fp8(SA * x[t][row][k]),
//   row=(mtg>>2)*64+(mtg&3)*16+(lane&15), k = i*32 + (lane>>4)*8 + j
__global__ __launch_bounds__(256)
void embed_pack(const int* __restrict__ tokens, const float* __restrict__ emb,
                unsigned char* __restrict__ Xp) {
    int gtid = blockIdx.x * 256 + threadIdx.x;   // one 8-byte chunk each
    if (gtid >= T_ * 8 * 8 * 64) return;
    int lane = gtid & 63;
    int rest = gtid >> 6;
    int i    = rest & 7;  rest >>= 3;
    int mtg  = rest & 7;
    int t    = rest >> 3;
    int row  = (mtg >> 2) * 64 + (mtg & 3) * 16 + (lane & 15);
    int k0   = i * 32 + (lane >> 4) * 8;
    const float* erow = emb + (size_t)tokens[row * T_ + t] * E_;
    unsigned char v[8];
#pragma unroll
    for (int j = 0; j < 8; ++j) {
        int e = k0 + j;
        v[j] = f2fp8(e < E_ ? SA_ * erow[e] : 0.f);
    }
    *reinterpret_cast<uint2*>(Xp + (size_t)gtid * 8) = *reinterpret_cast<const uint2*>(v);
}

// ---------------- weight pack: fp32 [K][Ncols] -> fp8 MFMA B-frag layout ----
// out[(((ut*KB + i)*NG + g)*64 + lane)*8 + j] = fp8(SB * W[k][g*U_+ut*16+(lane&15)])
__global__ __launch_bounds__(256)
void pack_w(const float* __restrict__ W, int K, int Ncols, int NG, int KB,
            unsigned char* __restrict__ out) {
    int gtid = blockIdx.x * 256 + threadIdx.x;
    int lane = gtid & 63;
    int rest = gtid >> 6;
    int g = rest % NG; rest /= NG;
    int i = rest % KB;
    int ut = rest / KB;
    if (ut >= U_ / 16) return;
    int col = g * U_ + ut * 16 + (lane & 15);
    int k0 = i * 32 + (lane >> 4) * 8;
    unsigned char v[8];
#pragma unroll
    for (int j = 0; j < 8; ++j) {
        int k = k0 + j;
        v[j] = f2fp8(k < K ? SB_ * W[(size_t)k * Ncols + col] : 0.f);
    }
    *reinterpret_cast<uint2*>(out + (size_t)gtid * 8) = *reinterpret_cast<const uint2*>(v);
}

// ---------------- fused LSTM step (fp8 MFMA), wave = K-eighth ----------------
// grid 256, XCD-swizzled (xcd = b&7 owns 16 consecutive ut; mh twins adjacent).
// 8 waves (kq 0..7), 16 MFMA/iter (4 gates x 4 row-frags), double-buffered.
__global__ __launch_bounds__(512)
void lstm_step_mfma(const unsigned char* __restrict__ A0p, int kb0,
                    const unsigned char* __restrict__ Wp0,
                    const unsigned char* __restrict__ A1p, int kb1,
                    const unsigned char* __restrict__ Wp1,
                    const float* __restrict__ bias,
                    float* __restrict__ c,
                    unsigned char* __restrict__ h_out /* packed fp8 */) {
    const int tid  = threadIdx.x;
    const int lane = tid & 63;
    const int kq   = tid >> 6;     // 0..7
    const int b    = blockIdx.x;
    const int s    = b >> 3;
    const int ut   = (b & 7) * 16 + (s >> 1);
    const int mh   = s & 1;

    const unsigned char* a0 = A0p + ((size_t)(mh * 4) * kb0) * 512 + lane * 8;
    const unsigned char* a1 = A1p + ((size_t)(mh * 4) * kb1) * 512 + lane * 8;
    const unsigned char* w0 = Wp0 + ((size_t)(ut * kb0) * 4) * 512 + lane * 8;
    const unsigned char* w1 = Wp1 + ((size_t)(ut * kb1) * 4) * 512 + lane * 8;

    f32x4 acc[4][4];   // [gate][mt]
#pragma unroll
    for (int g = 0; g < 4; ++g)
#pragma unroll
        for (int mt = 0; mt < 4; ++mt) acc[g][mt] = f32x4{0.f, 0.f, 0.f, 0.f};

    auto LOAD = [&](int i, long* a, long* bfr) {
        if (i < kb0) {
#pragma unroll
            for (int mt = 0; mt < 4; ++mt)
                a[mt] = *reinterpret_cast<const long*>(a0 + (size_t)(mt * kb0 + i) * 512);
#pragma unroll
            for (int g = 0; g < 4; ++g)
                bfr[g] = *reinterpret_cast<const long*>(w0 + (size_t)(i * 4 + g) * 512);
        } else {
            int ii = i - kb0;
#pragma unroll
            for (int mt = 0; mt < 4; ++mt)
                a[mt] = *reinterpret_cast<const long*>(a1 + (size_t)(mt * kb1 + ii) * 512);
#pragma unroll
            for (int g = 0; g < 4; ++g)
                bfr[g] = *reinterpret_cast<const long*>(w1 + (size_t)(ii * 4 + g) * 512);
        }
    };
#define MFMA_ALL(aa, bb)                                                         \
    {                                                                            \
        __builtin_amdgcn_s_setprio(1);                                           \
        _Pragma("unroll")                                                        \
        for (int g = 0; g < 4; ++g)                                              \
            _Pragma("unroll")                                                    \
            for (int mt = 0; mt < 4; ++mt)                                       \
                acc[g][mt] = __builtin_amdgcn_mfma_f32_16x16x32_fp8_fp8(         \
                    aa[mt], bb[g], acc[g][mt], 0, 0, 0);                         \
        __builtin_amdgcn_s_setprio(0);                                           \
    }

    const int KBt = kb0 + kb1;        // 72 or 128 (divisible by 8)
    const int KBq = KBt >> 3;
    const int beg = kq * KBq;
    const int end = beg + KBq;

    long aA[4], bA[4], aB[4], bB[4];
    int i = beg;
    LOAD(i, aA, bA);
    for (; i + 1 < end; i += 2) {
        LOAD(i + 1, aB, bB);
        MFMA_ALL(aA, bA);
        if (i + 2 < end) LOAD(i + 2, aA, bA);
        MFMA_ALL(aB, bB);
    }
    if (i < end) MFMA_ALL(aA, bA);
#undef MFMA_ALL

    // kq-partial reduction, one gate at a time through a 32KB LDS buffer
    __shared__ float zs[8][64][16];
    const int lr = tid >> 3;          // 0..63
    const int u0 = (tid & 7) * 2;     // 0,2,..,14
    float zg2[4][2];
#pragma unroll
    for (int g = 0; g < 4; ++g) {
        __syncthreads();
#pragma unroll
        for (int mt = 0; mt < 4; ++mt)
#pragma unroll
            for (int r = 0; r < 4; ++r)
                zs[kq][mt * 16 + (lane >> 4) * 4 + r][lane & 15] = acc[g][mt][r];
        __syncthreads();
        float s0 = 0.f, s1 = 0.f;
#pragma unroll
        for (int w8 = 0; w8 < 8; ++w8) {
            s0 += zs[w8][lr][u0];
            s1 += zs[w8][lr][u0 + 1];
        }
        zg2[g][0] = s0;
        zg2[g][1] = s1;
    }

    // fused cell update for 2 units (rescale acc by 1/(SA*SB) before bias)
    const int grow = mh * 64 + lr;
    const int unit = ut * 16 + u0;
    const float2 bi  = *reinterpret_cast<const float2*>(&bias[unit]);
    const float2 bfv = *reinterpret_cast<const float2*>(&bias[U_ + unit]);
    const float2 bgv = *reinterpret_cast<const float2*>(&bias[2 * U_ + unit]);
    const float2 bov = *reinterpret_cast<const float2*>(&bias[3 * U_ + unit]);
    float2 cv = *reinterpret_cast<float2*>(&c[(size_t)grow * U_ + unit]);

    float cn[2];
    unsigned char hv[2];
#pragma unroll
    for (int e = 0; e < 2; ++e) {
        float zi = zg2[0][e] * INV_SASB_ + (e ? bi.y : bi.x);
        float zf = zg2[1][e] * INV_SASB_ + (e ? bfv.y : bfv.x);
        float zg = zg2[2][e] * INV_SASB_ + (e ? bgv.y : bgv.x);
        float zo = zg2[3][e] * INV_SASB_ + (e ? bov.y : bov.x);
        float si = 1.f / (1.f + __expf(-zi));
        float sf = 1.f / (1.f + __expf(-zf));
        float so = 1.f / (1.f + __expf(-zo));
        float tg = tanhf(zg);
        float cc = sf * (e ? cv.y : cv.x) + si * tg;
        cn[e] = cc;
        hv[e] = f2fp8(SA_ * so * tanhf(cc));
    }
    *reinterpret_cast<float2*>(&c[(size_t)grow * U_ + unit]) = make_float2(cn[0], cn[1]);

    // packed h write (same fragment layout as A-frags with kb=64), fp8 bytes
    const int mt = lr >> 4;
    const int cl = lr & 15;
    const int fi = (mh * 4 + mt) * 64 + (unit >> 5);
    const int lp = ((unit >> 3) & 3) * 16 + cl;
    uchar2 hv2; hv2.x = hv[0]; hv2.y = hv[1];
    *reinterpret_cast<uchar2*>(&h_out[(size_t)fi * 512 + lp * 8 + (unit & 7)]) = hv2;
}

// ---------------- head: y = relu((h1 @ Wd)/512 + bd); fp8 operands ----------
__global__ __launch_bounds__(256)
void head_mfma(const unsigned char* __restrict__ h1p,
               const unsigned char* __restrict__ Wdp,
               const float* __restrict__ bd, float* __restrict__ y) {
    const int lane = threadIdx.x & 63;
    const int w    = threadIdx.x >> 6;  // k-split wave
    const int ut   = blockIdx.x & 127;
    const int mh   = blockIdx.x >> 7;

    const unsigned char* ap = h1p + ((size_t)(mh * 4) * 64) * 512 + lane * 8;
    const unsigned char* wp = Wdp + (size_t)(ut * 64 + w * 16) * 512 + lane * 8;

    f32x4 acc[4];
#pragma unroll
    for (int mt = 0; mt < 4; ++mt) acc[mt] = f32x4{0.f, 0.f, 0.f, 0.f};

    auto LOADH = [&](int i, long* a, long& b) {
        b = *reinterpret_cast<const long*>(wp + (size_t)i * 512);
        int kb = w * 16 + i;
#pragma unroll
        for (int mt = 0; mt < 4; ++mt)
            a[mt] = *reinterpret_cast<const long*>(ap + (size_t)(mt * 64 + kb) * 512);
    };

    long aA[4], bA, aB[4], bB;
    LOADH(0, aA, bA);
    for (int i = 0; i < 16; i += 2) {
        LOADH(i + 1, aB, bB);
#pragma unroll
        for (int mt = 0; mt < 4; ++mt)
            acc[mt] = __builtin_amdgcn_mfma_f32_16x16x32_fp8_fp8(aA[mt], bA, acc[mt], 0, 0, 0);
        if (i + 2 < 16) LOADH(i + 2, aA, bA);
#pragma unroll
        for (int mt = 0; mt < 4; ++mt)
            acc[mt] = __builtin_amdgcn_mfma_f32_16x16x32_fp8_fp8(aB[mt], bB, acc[mt], 0, 0, 0);
    }

    __shared__ float zs[4][64][16];
#pragma unroll
    for (int mt = 0; mt < 4; ++mt)
#pragma unroll
        for (int r = 0; r < 4; ++r)
            zs[w][mt * 16 + (lane >> 4) * 4 + r][lane & 15] = acc[mt][r];
    __syncthreads();

    const int tid = threadIdx.x;
    const int lr  = tid >> 2;
    const int u4  = (tid & 3) * 4;
    const int grow = mh * 64 + lr;
    const int gu   = ut * 16 + u4;

    float4 s0 = *reinterpret_cast<float4*>(&zs[0][lr][u4]);
    float4 s1 = *reinterpret_cast<float4*>(&zs[1][lr][u4]);
    float4 s2 = *reinterpret_cast<float4*>(&zs[2][lr][u4]);
    float4 s3 = *reinterpret_cast<float4*>(&zs[3][lr][u4]);
    const float4 bb = *reinterpret_cast<const float4*>(&bd[gu]);
    float4 r;
    r.x = (s0.x + s1.x + s2.x + s3.x) * INV_SASB_ + bb.x;
    r.y = (s0.y + s1.y + s2.y + s3.y) * INV_SASB_ + bb.y;
    r.z = (s0.z + s1.z + s2.z + s3.z) * INV_SASB_ + bb.z;
    r.w = (s0.w + s1.w + s2.w + s3.w) * INV_SASB_ + bb.w;
    r.x = r.x > 0.f ? r.x : 0.f;
    r.y = r.y > 0.f ? r.y : 0.f;
    r.z = r.z > 0.f ? r.z : 0.f;
    r.w = r.w > 0.f ? r.w : 0.f;
    *reinterpret_cast<float4*>(&y[(size_t)grow * U_ + gu]) = r;
}

// ---------------- out[b] = sigmoid(y[b,:] @ Wo + bo) ----------------
__global__ __launch_bounds__(256)
void head2(const float* __restrict__ y, const float* __restrict__ Wo,
           const float* __restrict__ bo, float* __restrict__ out) {
    __shared__ float red[256];
    const int b = blockIdx.x;
    const int tid = threadIdx.x;
    float s = 0.f;
    for (int u = tid; u < U_; u += 256) s += y[(size_t)b * U_ + u] * Wo[u];
    red[tid] = s;
    __syncthreads();
    for (int off = 128; off > 0; off >>= 1) {
        if (tid < off) red[tid] += red[tid + off];
        __syncthreads();
    }
    if (tid == 0) out[b] = 1.f / (1.f + __expf(-(red[0] + bo[0])));
}

extern "C" void kernel_launch(void* const* d_in, const int* in_sizes, int n_in,
                              void* d_out, int out_size, void* d_ws, size_t ws_size,
                              hipStream_t stream) {
    const int*   tokens = (const int*)  d_in[0];
    const float* emb    = (const float*)d_in[1];
    const float* W0     = (const float*)d_in[2];
    const float* U0     = (const float*)d_in[3];
    const float* b0     = (const float*)d_in[4];
    const float* W1     = (const float*)d_in[5];
    const float* U1     = (const float*)d_in[6];
    const float* b1     = (const float*)d_in[7];
    const float* Wd     = (const float*)d_in[8];
    const float* bd     = (const float*)d_in[9];
    const float* Wo     = (const float*)d_in[10];
    const float* bo     = (const float*)d_in[11];

    // ws layout (bytes); total ~62 MB
    char* base = (char*)d_ws;
    unsigned char* h0a = (unsigned char*)(base + 0);         // 256 KB (packed fp8)
    unsigned char* h1a = (unsigned char*)(base + 262144);    // 256 KB
    float*         c0  = (float*)        (base + 524288);    // 1 MB
    float*         c1  = (float*)        (base + 1572864);   // 1 MB
    unsigned char* h0b = (unsigned char*)(base + 2621440);   // 256 KB
    unsigned char* h1b = (unsigned char*)(base + 2883584);   // 256 KB
    unsigned char* Xp  = (unsigned char*)(base + 3145728);   // 2.62 MB
    float*         yb  = (float*)        (base + 3145728);   // overlays Xp (dead by head)
    unsigned char* W0p = (unsigned char*)(base + 5767168);   // 2 MB
    unsigned char* U0p = (unsigned char*)(base + 7864320);   // 16 MB
    unsigned char* W1p = (unsigned char*)(base + 24641536);  // 16 MB
    unsigned char* U1p = (unsigned char*)(base + 41418752);  // 16 MB
    unsigned char* Wdp = (unsigned char*)(base + 58195968);  // 4 MB

    // zero h0a, h1a, c0, c1 (contiguous 2.56 MB)
    hipMemsetAsync(d_ws, 0, 2621440, stream);

    embed_pack<<<(T_ * 8 * 8 * 64 + 255) / 256, 256, 0, stream>>>(tokens, emb, Xp);
    pack_w<<<1024, 256, 0, stream>>>(W0, E_, G4_, 4, 8,  W0p);
    pack_w<<<8192, 256, 0, stream>>>(U0, U_, G4_, 4, 64, U0p);
    pack_w<<<8192, 256, 0, stream>>>(W1, U_, G4_, 4, 64, W1p);
    pack_w<<<8192, 256, 0, stream>>>(U1, U_, G4_, 4, 64, U1p);
    pack_w<<<2048, 256, 0, stream>>>(Wd, U_, U_,  1, 64, Wdp);

    for (int t = 0; t < T_; ++t) {
        const unsigned char* h0in  = (t & 1) ? h0b : h0a;
        unsigned char*       h0out = (t & 1) ? h0a : h0b;
        const unsigned char* h1in  = (t & 1) ? h1b : h1a;
        unsigned char*       h1out = (t & 1) ? h1a : h1b;
        lstm_step_mfma<<<256, 512, 0, stream>>>(Xp + (size_t)t * 8 * 8 * 512, 8, W0p,
                                                h0in, 64, U0p, b0, c0, h0out);
        lstm_step_mfma<<<256, 512, 0, stream>>>(h0out, 64, W1p,
                                                h1in, 64, U1p, b1, c1, h1out);
    }
    // t=79 (odd) wrote the 'a' buffers
    head_mfma<<<256, 256, 0, stream>>>(h1a, Wdp, bd, yb);
    head2<<<B_, 256, 0, stream>>>(yb, Wo, bo, (float*)d_out);
}